// Round 1
// baseline (1453.947 us; speedup 1.0000x reference)
//
#include <hip/hip_runtime.h>

// Problem constants
#define MR 50176        // B_*N = 1024*49 rows
#define DIMC 512
#define NHEADS 16
#define HDIM 32
#define NWIN 49
#define NBATCH 1024
#define ATTN_SCALE 0.17677669529663689f  // 32^-0.5

typedef short bf16x8 __attribute__((ext_vector_type(8)));
typedef float f32x4 __attribute__((ext_vector_type(4)));

__device__ __forceinline__ unsigned short f2bf(float f) {
  union { float f; unsigned int u; } v; v.f = f;
  unsigned int u = v.u;
  u += 0x7FFFu + ((u >> 16) & 1u);   // round-to-nearest-even
  return (unsigned short)(u >> 16);
}
__device__ __forceinline__ float bf2f(short s) {
  union { unsigned int u; float f; } v;
  v.u = ((unsigned int)(unsigned short)s) << 16;
  return v.f;
}

// ---------------------------------------------------------------------------
// Weight prep: Wt[n][k] = bf16(W[k*ldw + coloff + n]), 512x512 slice.
// Coalesced reads; scattered 2B writes absorbed by L2 (only 0.5MB/matrix).
// ---------------------------------------------------------------------------
__global__ void prep_w(const float* __restrict__ W, int ldw, int coloff,
                       short* __restrict__ Wt) {
  int idx = blockIdx.x * 256 + threadIdx.x;   // 0 .. 262143
  int k = idx >> 9;
  int n = idx & 511;
  float v = W[(size_t)k * ldw + coloff + n];
  Wt[(size_t)n * DIMC + k] = (short)f2bf(v);
}

// ---------------------------------------------------------------------------
// GEMM: Y[M,512] = X[M,512] @ Wt^T + bias   (Wt stored [n][k] bf16)
// 128x128 tile, BK=32, 256 threads = 4 waves in 2x2, 4x4 MFMA 16x16x32 tiles.
// LDS stride 40 shorts: 16B-aligned ds_read_b128, 2-way banks (free).
// ---------------------------------------------------------------------------
template <bool IN_BF16, bool OUT_F32>
__global__ __launch_bounds__(256) void gemm128(
    const void* __restrict__ Xv, const short* __restrict__ Wt,
    const float* __restrict__ bias, void* __restrict__ Yv) {
  __shared__ short As[128 * 40];
  __shared__ short Bs[128 * 40];

  const int t = threadIdx.x;
  const int n0 = blockIdx.x * 128;
  const int row0 = blockIdx.y * 128;
  const int wave = t >> 6, lane = t & 63;
  const int wm = wave >> 1, wn = wave & 1;
  const int l15 = lane & 15;
  const int kg = (lane >> 4) << 3;    // k-group offset 0,8,16,24

  f32x4 acc[4][4];
#pragma unroll
  for (int i = 0; i < 4; ++i)
#pragma unroll
    for (int j = 0; j < 4; ++j) acc[i][j] = {0.f, 0.f, 0.f, 0.f};

  for (int kt = 0; kt < 16; ++kt) {
    const int k0 = kt << 5;
    __syncthreads();
    // ---- stage A tile (128 rows x 32 k) ----
    if constexpr (!IN_BF16) {
      const float* X = (const float*)Xv;
      const int ar = t >> 3, ac = (t & 7) << 2;
#pragma unroll
      for (int rr = 0; rr < 128; rr += 32) {
        const float4 v =
            *(const float4*)(X + (size_t)(row0 + ar + rr) * DIMC + k0 + ac);
        unsigned int lo = (unsigned int)f2bf(v.x) | ((unsigned int)f2bf(v.y) << 16);
        unsigned int hi = (unsigned int)f2bf(v.z) | ((unsigned int)f2bf(v.w) << 16);
        *(uint2*)&As[(ar + rr) * 40 + ac] = make_uint2(lo, hi);
      }
    } else {
      const short* X = (const short*)Xv;
      const int ar = t >> 2, ac = (t & 3) << 3;
#pragma unroll
      for (int rr = 0; rr < 128; rr += 64) {
        uint4 v = *(const uint4*)(X + (size_t)(row0 + ar + rr) * DIMC + k0 + ac);
        *(uint4*)&As[(ar + rr) * 40 + ac] = v;
      }
    }
    // ---- stage B tile (128 n-rows x 32 k), already bf16 [n][k] ----
    {
      const int br = t >> 2, bc = (t & 3) << 3;
#pragma unroll
      for (int rr = 0; rr < 128; rr += 64) {
        uint4 v = *(const uint4*)(Wt + (size_t)(n0 + br + rr) * DIMC + k0 + bc);
        *(uint4*)&Bs[(br + rr) * 40 + bc] = v;
      }
    }
    __syncthreads();
    // ---- compute ----
    bf16x8 af[4], bfr[4];
#pragma unroll
    for (int i = 0; i < 4; ++i)
      af[i] = *(const bf16x8*)&As[(wm * 64 + i * 16 + l15) * 40 + kg];
#pragma unroll
    for (int j = 0; j < 4; ++j)
      bfr[j] = *(const bf16x8*)&Bs[(wn * 64 + j * 16 + l15) * 40 + kg];
#pragma unroll
    for (int i = 0; i < 4; ++i)
#pragma unroll
      for (int j = 0; j < 4; ++j)
        acc[i][j] = __builtin_amdgcn_mfma_f32_16x16x32_bf16(af[i], bfr[j],
                                                            acc[i][j], 0, 0, 0);
  }

  // ---- epilogue: C/D layout col=lane&15, row=(lane>>4)*4+reg ----
  const int rbase = row0 + wm * 64 + ((lane >> 4) << 2);
  const int cbase = n0 + wn * 64 + l15;
#pragma unroll
  for (int j = 0; j < 4; ++j) {
    const int col = cbase + j * 16;
    const float bv = bias[col];
#pragma unroll
    for (int i = 0; i < 4; ++i) {
#pragma unroll
      for (int r = 0; r < 4; ++r) {
        const int row = rbase + i * 16 + r;
        const float val = acc[i][j][r] + bv;
        if constexpr (OUT_F32)
          ((float*)Yv)[(size_t)row * DIMC + col] = val;
        else
          ((short*)Yv)[(size_t)row * DIMC + col] = (short)f2bf(val);
      }
    }
  }
}

// ---------------------------------------------------------------------------
// Attention: one block per (b,h). 256 threads = 4 waves; wave handles query
// rows n = wave, wave+4, ... Lane = key index for QK^T + softmax; lanes 0..31
// = head dim for PV. q = q1*SCALE*gw staged fp32 in LDS. out may alias kbuf.
// ---------------------------------------------------------------------------
__global__ __launch_bounds__(256) void attn_win(
    const short* __restrict__ kbuf, const short* __restrict__ qbuf,
    const short* __restrict__ vbuf, const short* __restrict__ gbuf,
    const float* __restrict__ a_scalar, short* __restrict__ obuf) {
  __shared__ float kls[NWIN][33];
  __shared__ float vls[NWIN][33];
  __shared__ float qls[NWIN][33];

  const int bh = blockIdx.x;
  const int b = bh >> 4, h = bh & 15;
  const int t = threadIdx.x;
  const float aval = a_scalar[0];
  const size_t base = (size_t)b * NWIN * DIMC + h * HDIM;

  for (int idx = t; idx < NWIN * HDIM; idx += 256) {
    const int n = idx >> 5, d = idx & 31;
    const size_t g = base + (size_t)n * DIMC + d;
    kls[n][d] = bf2f(kbuf[g]);
    vls[n][d] = bf2f(vbuf[g]);
    qls[n][d] = ATTN_SCALE * bf2f(qbuf[g]) * bf2f(gbuf[g]);
  }
  __syncthreads();

  const int wave = t >> 6, lane = t & 63;
  for (int n = wave; n < NWIN; n += 4) {
    // S[n, lane] over d
    float s = -INFINITY;
    if (lane < NWIN) {
      float a = 0.f;
#pragma unroll
      for (int d = 0; d < HDIM; ++d) a += qls[n][d] * kls[lane][d];
      s = a;
    }
    float m = s;
#pragma unroll
    for (int off = 32; off; off >>= 1) m = fmaxf(m, __shfl_xor(m, off, 64));
    float p = (lane < NWIN) ? __expf(s - m) : 0.f;
    float sum = p;
#pragma unroll
    for (int off = 32; off; off >>= 1) sum += __shfl_xor(sum, off, 64);
    p *= (1.0f / sum);
    // PV: lane (0..31) = head dim; broadcast P via shfl (all lanes active)
    float out = 0.f;
    for (int m2 = 0; m2 < NWIN; ++m2) {
      const float pm = __shfl(p, m2, 64);
      out += pm * vls[m2][lane & 31];
    }
    if (lane < HDIM) {
      out += aval * vls[n][lane];
      obuf[base + (size_t)n * DIMC + lane] = (short)f2bf(out);
    }
  }
}

// ---------------------------------------------------------------------------
extern "C" void kernel_launch(void* const* d_in, const int* in_sizes, int n_in,
                              void* d_out, int out_size, void* d_ws,
                              size_t ws_size, hipStream_t stream) {
  const float* x     = (const float*)d_in[0];
  const float* x2    = (const float*)d_in[1];
  const float* x3    = (const float*)d_in[2];
  const float* Wqkv  = (const float*)d_in[3];
  const float* bqkv  = (const float*)d_in[4];
  const float* Wqkv2 = (const float*)d_in[5];
  const float* bqkv2 = (const float*)d_in[6];
  const float* Wgw   = (const float*)d_in[7];
  const float* bgw   = (const float*)d_in[8];
  const float* Wproj = (const float*)d_in[9];
  const float* bproj = (const float*)d_in[10];
  const float* a     = (const float*)d_in[11];

  char* ws = (char*)d_ws;
  const size_t WSZ = (size_t)DIMC * DIMC * sizeof(short);       // 0.5 MB
  const size_t BSZ = (size_t)MR * DIMC * sizeof(short);         // 51.4 MB
  short* wt_k = (short*)(ws);
  short* wt_q = (short*)(ws + WSZ);
  short* wt_v = (short*)(ws + 2 * WSZ);
  short* wt_g = (short*)(ws + 3 * WSZ);
  short* wt_p = (short*)(ws + 4 * WSZ);
  char* bufs = ws + 5 * WSZ;
  short* kbuf = (short*)(bufs);
  short* qbuf = (short*)(bufs + BSZ);
  short* vbuf = (short*)(bufs + 2 * BSZ);
  short* gbuf = (short*)(bufs + 3 * BSZ);
  short* obuf = kbuf;  // k is dead after attention staging; reuse region

  // 1) weight transpose+convert (bf16 [n][k])
  prep_w<<<1024, 256, 0, stream>>>(Wqkv, 1536, 512, wt_k);
  prep_w<<<1024, 256, 0, stream>>>(Wqkv2, 1536, 0, wt_q);
  prep_w<<<1024, 256, 0, stream>>>(Wqkv2, 1536, 1024, wt_v);
  prep_w<<<1024, 256, 0, stream>>>(Wgw, 512, 0, wt_g);
  prep_w<<<1024, 256, 0, stream>>>(Wproj, 512, 0, wt_p);

  // 2) stage-1 GEMMs (fp32 in -> bf16 out)
  dim3 gg(4, MR / 128);
  gemm128<false, false><<<gg, 256, 0, stream>>>(x, wt_k, bqkv + 512, kbuf);
  gemm128<false, false><<<gg, 256, 0, stream>>>(x3, wt_q, bqkv2, qbuf);
  gemm128<false, false><<<gg, 256, 0, stream>>>(x3, wt_v, bqkv2 + 1024, vbuf);
  gemm128<false, false><<<gg, 256, 0, stream>>>(x2, wt_g, bgw, gbuf);

  // 3) windowed gated attention
  attn_win<<<NBATCH * NHEADS, 256, 0, stream>>>(kbuf, qbuf, vbuf, gbuf, a, obuf);

  // 4) projection (bf16 in -> fp32 out)
  gemm128<true, true><<<gg, 256, 0, stream>>>(obuf, wt_p, bproj, (float*)d_out);
}

// Round 2
// 711.607 us; speedup vs baseline: 2.0432x; 2.0432x over previous
//
#include <hip/hip_runtime.h>

// Problem constants
#define MR 50176        // B_*N = 1024*49 rows
#define DIMC 512
#define NHEADS 16
#define HDIM 32
#define NWIN 49
#define NBATCH 1024
#define ATTN_SCALE 0.17677669529663689f  // 32^-0.5

typedef short bf16x8 __attribute__((ext_vector_type(8)));
typedef float f32x4 __attribute__((ext_vector_type(4)));

__device__ __forceinline__ unsigned short f2bf(float f) {
  union { float f; unsigned int u; } v; v.f = f;
  unsigned int u = v.u;
  u += 0x7FFFu + ((u >> 16) & 1u);   // round-to-nearest-even
  return (unsigned short)(u >> 16);
}
__device__ __forceinline__ float bits_f(unsigned int u) {
  union { unsigned int u; float f; } v; v.u = u; return v.f;
}

// ---------------------------------------------------------------------------
// Weight prep: Wt[n][k] = bf16(W[k*ldw + coloff + n]), 512x512 slice.
// ---------------------------------------------------------------------------
__global__ void prep_w(const float* __restrict__ W, int ldw, int coloff,
                       short* __restrict__ Wt) {
  int idx = blockIdx.x * 256 + threadIdx.x;   // 0 .. 262143
  int k = idx >> 9;
  int n = idx & 511;
  float v = W[(size_t)k * ldw + coloff + n];
  Wt[(size_t)n * DIMC + k] = (short)f2bf(v);
}

// ---------------------------------------------------------------------------
// GEMM: Y[M,512] = X[M,512] @ Wt^T + bias   (Wt stored [n][k] bf16)
// 128x128 tile, BK=32, 256 threads = 4 waves in 2x2, 4x4 MFMA 16x16x32 tiles.
// ---------------------------------------------------------------------------
template <bool IN_BF16, bool OUT_F32>
__global__ __launch_bounds__(256) void gemm128(
    const void* __restrict__ Xv, const short* __restrict__ Wt,
    const float* __restrict__ bias, void* __restrict__ Yv) {
  __shared__ short As[128 * 40];
  __shared__ short Bs[128 * 40];

  const int t = threadIdx.x;
  const int n0 = blockIdx.x * 128;
  const int row0 = blockIdx.y * 128;
  const int wave = t >> 6, lane = t & 63;
  const int wm = wave >> 1, wn = wave & 1;
  const int l15 = lane & 15;
  const int kg = (lane >> 4) << 3;    // k-group offset 0,8,16,24

  f32x4 acc[4][4];
#pragma unroll
  for (int i = 0; i < 4; ++i)
#pragma unroll
    for (int j = 0; j < 4; ++j) acc[i][j] = {0.f, 0.f, 0.f, 0.f};

  for (int kt = 0; kt < 16; ++kt) {
    const int k0 = kt << 5;
    __syncthreads();
    if constexpr (!IN_BF16) {
      const float* X = (const float*)Xv;
      const int ar = t >> 3, ac = (t & 7) << 2;
#pragma unroll
      for (int rr = 0; rr < 128; rr += 32) {
        const float4 v =
            *(const float4*)(X + (size_t)(row0 + ar + rr) * DIMC + k0 + ac);
        unsigned int lo = (unsigned int)f2bf(v.x) | ((unsigned int)f2bf(v.y) << 16);
        unsigned int hi = (unsigned int)f2bf(v.z) | ((unsigned int)f2bf(v.w) << 16);
        *(uint2*)&As[(ar + rr) * 40 + ac] = make_uint2(lo, hi);
      }
    } else {
      const short* X = (const short*)Xv;
      const int ar = t >> 2, ac = (t & 3) << 3;
#pragma unroll
      for (int rr = 0; rr < 128; rr += 64) {
        uint4 v = *(const uint4*)(X + (size_t)(row0 + ar + rr) * DIMC + k0 + ac);
        *(uint4*)&As[(ar + rr) * 40 + ac] = v;
      }
    }
    {
      const int br = t >> 2, bc = (t & 3) << 3;
#pragma unroll
      for (int rr = 0; rr < 128; rr += 64) {
        uint4 v = *(const uint4*)(Wt + (size_t)(n0 + br + rr) * DIMC + k0 + bc);
        *(uint4*)&Bs[(br + rr) * 40 + bc] = v;
      }
    }
    __syncthreads();
    bf16x8 af[4], bfr[4];
#pragma unroll
    for (int i = 0; i < 4; ++i)
      af[i] = *(const bf16x8*)&As[(wm * 64 + i * 16 + l15) * 40 + kg];
#pragma unroll
    for (int j = 0; j < 4; ++j)
      bfr[j] = *(const bf16x8*)&Bs[(wn * 64 + j * 16 + l15) * 40 + kg];
#pragma unroll
    for (int i = 0; i < 4; ++i)
#pragma unroll
      for (int j = 0; j < 4; ++j)
        acc[i][j] = __builtin_amdgcn_mfma_f32_16x16x32_bf16(af[i], bfr[j],
                                                            acc[i][j], 0, 0, 0);
  }

  const int rbase = row0 + wm * 64 + (((t & 63) >> 4) << 2);
  const int cbase = n0 + wn * 64 + l15;
#pragma unroll
  for (int j = 0; j < 4; ++j) {
    const int col = cbase + j * 16;
    const float bv = bias[col];
#pragma unroll
    for (int i = 0; i < 4; ++i) {
#pragma unroll
      for (int r = 0; r < 4; ++r) {
        const int row = rbase + i * 16 + r;
        const float val = acc[i][j][r] + bv;
        if constexpr (OUT_F32)
          ((float*)Yv)[(size_t)row * DIMC + col] = val;
        else
          ((short*)Yv)[(size_t)row * DIMC + col] = (short)f2bf(val);
      }
    }
  }
}

// ---------------------------------------------------------------------------
// MFMA attention: ONE WINDOW PER WAVE (4 windows / 256-thread block).
// S = Q·K^T via 4x4 tiles of mfma_16x16x32 (K=32=head_dim, one step).
// Softmax: no max-sub (|s*scale| <~ 8, exp-safe); row-sum via 4 shfl_xor over
// the quad's 16 lanes; residual a·v folded into P's diagonal as a·l_n.
// PV: P through LDS (C-layout -> A-layout), V^T staged in LDS, 2 K-halves of
// 32 to keep P buffer at 64x40 (LDS 38.9 KB/block -> 4 blocks/CU).
// No __syncthreads: all LDS traffic is wave-private (in-wave DS ordering).
// ---------------------------------------------------------------------------
__global__ __launch_bounds__(256) void attn_mfma(
    const short* __restrict__ kbuf, const short* __restrict__ qbuf,
    const short* __restrict__ vbuf, const short* __restrict__ gbuf,
    const float* __restrict__ a_scalar, short* __restrict__ obuf) {
  __shared__ short pls[4][64 * 40];   // P (bf16), rows n=0..63, 32-col half
  __shared__ short vls[4][32 * 72];   // V^T (bf16), rows d=0..31, cols m=0..63

  const int t = threadIdx.x;
  const int w = t >> 6, lane = t & 63;
  const int l15 = lane & 15, q = lane >> 4, kg = q * 8;
  const int wid = blockIdx.x * 4 + w;
  const int b = wid >> 4, h = wid & 15;
  const size_t base = (size_t)b * (NWIN * DIMC) + (size_t)h * HDIM;
  const float aval = a_scalar[0];
  short* P = pls[w];
  short* VT = vls[w];

  // zero V^T (pad cols m=49..63 MUST be 0; uninit LDS could be NaN-pattern)
#pragma unroll
  for (int it = 0; it < 5; ++it) {
    int off = (it * 64 + lane) * 8;
    if (off < 32 * 72) *(uint4*)&VT[off] = make_uint4(0u, 0u, 0u, 0u);
  }

  // K fragments (B-operand): B[m][d], rows clamped to 48 (masked at exp)
  bf16x8 kf[4];
#pragma unroll
  for (int mj = 0; mj < 4; ++mj) {
    int m = mj * 16 + l15; if (m > 48) m = 48;
    kf[mj] = *(const bf16x8*)(kbuf + base + (size_t)m * DIMC + kg);
  }
  // Q fragments: q = bf16(q1 * gw); SCALE folded into exp argument
  bf16x8 qf[4];
#pragma unroll
  for (int mi = 0; mi < 4; ++mi) {
    int n = mi * 16 + l15; if (n > 48) n = 48;
    uint4 qa = *(const uint4*)(qbuf + base + (size_t)n * DIMC + kg);
    uint4 ga = *(const uint4*)(gbuf + base + (size_t)n * DIMC + kg);
    unsigned int* qa_ = (unsigned int*)&qa;
    unsigned int* ga_ = (unsigned int*)&ga;
    uint4 res;
    unsigned int* r_ = (unsigned int*)&res;
#pragma unroll
    for (int jj = 0; jj < 4; ++jj) {
      float lo = bits_f(qa_[jj] << 16) * bits_f(ga_[jj] << 16);
      float hi = bits_f(qa_[jj] & 0xffff0000u) * bits_f(ga_[jj] & 0xffff0000u);
      r_[jj] = (unsigned int)f2bf(lo) | ((unsigned int)f2bf(hi) << 16);
    }
    qf[mi] = *(bf16x8*)&res;
  }
  // stage V^T (49 rows x 32 d -> VT[d][m])
#pragma unroll
  for (int it = 0; it < 4; ++it) {
    int chunk = it * 64 + lane;
    if (chunk < 196) {
      int n = chunk >> 2, dc = (chunk & 3) * 8;
      uint4 v = *(const uint4*)(vbuf + base + (size_t)n * DIMC + dc);
      const short* vs = (const short*)&v;
#pragma unroll
      for (int j = 0; j < 8; ++j) VT[(dc + j) * 72 + n] = vs[j];
    }
  }

  // S = Q·K^T ; C-layout: row n = mi*16+q*4+r, col m = nj*16+l15
  f32x4 s[4][4];
#pragma unroll
  for (int mi = 0; mi < 4; ++mi)
#pragma unroll
    for (int nj = 0; nj < 4; ++nj) {
      f32x4 z = {0.f, 0.f, 0.f, 0.f};
      s[mi][nj] = __builtin_amdgcn_mfma_f32_16x16x32_bf16(qf[mi], kf[nj], z, 0, 0, 0);
    }

  // exp in place (reuse s as P-values), mask cols >= 49
#pragma unroll
  for (int mi = 0; mi < 4; ++mi)
#pragma unroll
    for (int nj = 0; nj < 4; ++nj) {
      const bool valid = (nj * 16 + l15) < NWIN;
#pragma unroll
      for (int r = 0; r < 4; ++r)
        s[mi][nj][r] = valid ? __expf(ATTN_SCALE * s[mi][nj][r]) : 0.f;
    }

  // row sums l_n (butterfly over the quad's 16 lanes)
  float lsum[4][4];
#pragma unroll
  for (int mi = 0; mi < 4; ++mi)
#pragma unroll
    for (int r = 0; r < 4; ++r) {
      float part = s[mi][0][r] + s[mi][1][r] + s[mi][2][r] + s[mi][3][r];
      part += __shfl_xor(part, 1, 64);
      part += __shfl_xor(part, 2, 64);
      part += __shfl_xor(part, 4, 64);
      part += __shfl_xor(part, 8, 64);
      lsum[mi][r] = part;
    }

  // PV through LDS in two 32-col halves; diag += a*l_n at store time
  f32x4 o[4][2];
#pragma unroll
  for (int mi = 0; mi < 4; ++mi)
#pragma unroll
    for (int dj = 0; dj < 2; ++dj) o[mi][dj] = {0.f, 0.f, 0.f, 0.f};

#pragma unroll
  for (int c = 0; c < 2; ++c) {
#pragma unroll
    for (int mi = 0; mi < 4; ++mi)
#pragma unroll
      for (int njh = 0; njh < 2; ++njh) {
        const int nj = c * 2 + njh;
        const int m = nj * 16 + l15;
#pragma unroll
        for (int r = 0; r < 4; ++r) {
          const int n = mi * 16 + q * 4 + r;
          float val = s[mi][nj][r];
          if (m == n) val += aval * lsum[mi][r];
          P[n * 40 + njh * 16 + l15] = (short)f2bf(val);
        }
      }
    // A-frags from P half, B-frags from VT cols c*32.. ; 8 MFMA
    bf16x8 bfr[2];
#pragma unroll
    for (int dj = 0; dj < 2; ++dj)
      bfr[dj] = *(const bf16x8*)&VT[(dj * 16 + l15) * 72 + c * 32 + kg];
#pragma unroll
    for (int mi = 0; mi < 4; ++mi) {
      bf16x8 af = *(const bf16x8*)&P[(mi * 16 + l15) * 40 + kg];
#pragma unroll
      for (int dj = 0; dj < 2; ++dj)
        o[mi][dj] = __builtin_amdgcn_mfma_f32_16x16x32_bf16(af, bfr[dj],
                                                            o[mi][dj], 0, 0, 0);
    }
  }

  // epilogue: out = o / l_n  (residual already folded via diagonal)
#pragma unroll
  for (int mi = 0; mi < 4; ++mi)
#pragma unroll
    for (int r = 0; r < 4; ++r) {
      const int n = mi * 16 + q * 4 + r;
      if (n < NWIN) {
        const float rl = 1.0f / lsum[mi][r];
#pragma unroll
        for (int dj = 0; dj < 2; ++dj)
          obuf[base + (size_t)n * DIMC + dj * 16 + l15] =
              (short)f2bf(o[mi][dj][r] * rl);
      }
    }
}

// ---------------------------------------------------------------------------
extern "C" void kernel_launch(void* const* d_in, const int* in_sizes, int n_in,
                              void* d_out, int out_size, void* d_ws,
                              size_t ws_size, hipStream_t stream) {
  const float* x     = (const float*)d_in[0];
  const float* x2    = (const float*)d_in[1];
  const float* x3    = (const float*)d_in[2];
  const float* Wqkv  = (const float*)d_in[3];
  const float* bqkv  = (const float*)d_in[4];
  const float* Wqkv2 = (const float*)d_in[5];
  const float* bqkv2 = (const float*)d_in[6];
  const float* Wgw   = (const float*)d_in[7];
  const float* bgw   = (const float*)d_in[8];
  const float* Wproj = (const float*)d_in[9];
  const float* bproj = (const float*)d_in[10];
  const float* a     = (const float*)d_in[11];

  char* ws = (char*)d_ws;
  const size_t WSZ = (size_t)DIMC * DIMC * sizeof(short);       // 0.5 MB
  const size_t BSZ = (size_t)MR * DIMC * sizeof(short);         // 51.4 MB
  short* wt_k = (short*)(ws);
  short* wt_q = (short*)(ws + WSZ);
  short* wt_v = (short*)(ws + 2 * WSZ);
  short* wt_g = (short*)(ws + 3 * WSZ);
  short* wt_p = (short*)(ws + 4 * WSZ);
  char* bufs = ws + 5 * WSZ;
  short* kbuf = (short*)(bufs);
  short* qbuf = (short*)(bufs + BSZ);
  short* vbuf = (short*)(bufs + 2 * BSZ);
  short* gbuf = (short*)(bufs + 3 * BSZ);
  short* obuf = kbuf;  // k consumed into registers before O stores; same slice

  prep_w<<<1024, 256, 0, stream>>>(Wqkv, 1536, 512, wt_k);
  prep_w<<<1024, 256, 0, stream>>>(Wqkv2, 1536, 0, wt_q);
  prep_w<<<1024, 256, 0, stream>>>(Wqkv2, 1536, 1024, wt_v);
  prep_w<<<1024, 256, 0, stream>>>(Wgw, 512, 0, wt_g);
  prep_w<<<1024, 256, 0, stream>>>(Wproj, 512, 0, wt_p);

  dim3 gg(4, MR / 128);
  gemm128<false, false><<<gg, 256, 0, stream>>>(x, wt_k, bqkv + 512, kbuf);
  gemm128<false, false><<<gg, 256, 0, stream>>>(x3, wt_q, bqkv2, qbuf);
  gemm128<false, false><<<gg, 256, 0, stream>>>(x3, wt_v, bqkv2 + 1024, vbuf);
  gemm128<false, false><<<gg, 256, 0, stream>>>(x2, wt_g, bgw, gbuf);

  attn_mfma<<<(NBATCH * NHEADS) / 4, 256, 0, stream>>>(kbuf, qbuf, vbuf, gbuf,
                                                       a, obuf);

  gemm128<true, true><<<gg, 256, 0, stream>>>(obuf, wt_p, bproj, (float*)d_out);
}

// Round 3
// 648.162 us; speedup vs baseline: 2.2432x; 1.0979x over previous
//
#include <hip/hip_runtime.h>

#define MR 50176        // B_*N = 1024*49 rows
#define DIMC 512
#define NHEADS 16
#define NWIN 49
#define NBATCH 1024
#define ATTN_SCALE 0.17677669529663689f  // 32^-0.5

typedef short bf16x8 __attribute__((ext_vector_type(8)));
typedef float f32x4 __attribute__((ext_vector_type(4)));
typedef unsigned int u32;

__device__ __forceinline__ unsigned short f2bf(float f) {
  union { float f; u32 u; } v; v.f = f;
  u32 u = v.u;
  u += 0x7FFFu + ((u >> 16) & 1u);   // round-to-nearest-even
  return (unsigned short)(u >> 16);
}
__device__ __forceinline__ float bits_f(u32 u) {
  union { u32 u; float f; } v; v.u = u; return v.f;
}

// ---------------------------------------------------------------------------
// Packed-swizzled bf16 layout for a [rows][512] matrix, 16B chunk units.
// Groups of 8 rows x 64 shorts (one "kline" of 8 chunks) = 1KB lines, chunk
// position XOR-swizzled by row&7 so GEMM frag reads are bank-conflict-free
// while global_load_lds DMA (wave-uniform LDS base + lane*16) stays legal.
// byte offset of chunk (row r, chunk c=k/8):
__device__ __forceinline__ size_t pk_chunk(int r, int c) {
  return (((size_t)(r >> 3) * 8 + (c >> 3)) * 64 +
          ((r & 7) * 8 + ((c & 7) ^ (r & 7)))) << 4;
}

typedef const __attribute__((address_space(1))) u32* gp_t;
typedef __attribute__((address_space(3))) u32* lp_t;
__device__ __forceinline__ void glds16(const void* g, void* l) {
  __builtin_amdgcn_global_load_lds((gp_t)g, (lp_t)l, 16, 0, 0);
}

// ---------------------------------------------------------------------------
// fp32 [rows][512] -> packed bf16. One thread per 16B chunk; output fully
// coalesced (tid*16 bytes), input reads whole 64B segments (permuted order).
// ---------------------------------------------------------------------------
__global__ __launch_bounds__(256) void conv_pack(const float* __restrict__ X,
                                                 short* __restrict__ Xp) {
  const int tid = blockIdx.x * 256 + threadIdx.x;
  const int li = tid & 63, gl = tid >> 6;
  const int kline = gl & 7, group = gl >> 3;
  const int rr = li >> 3, pp = li & 7;
  const int row = group * 8 + rr;
  const int k = kline * 64 + ((pp ^ rr) << 3);
  const float* src = X + (size_t)row * DIMC + k;
  const float4 a = *(const float4*)src;
  const float4 b = *(const float4*)(src + 4);
  u32 w0 = (u32)f2bf(a.x) | ((u32)f2bf(a.y) << 16);
  u32 w1 = (u32)f2bf(a.z) | ((u32)f2bf(a.w) << 16);
  u32 w2 = (u32)f2bf(b.x) | ((u32)f2bf(b.y) << 16);
  u32 w3 = (u32)f2bf(b.z) | ((u32)f2bf(b.w) << 16);
  ((uint4*)Xp)[tid] = make_uint4(w0, w1, w2, w3);
}

// ---------------------------------------------------------------------------
// All 5 weight slices transposed+converted into one packed bf16 [2560][512]:
// rows 0..511 Wk^T, 512..1023 Wq^T, 1024..1535 Wv^T, 1536..2047 Wg^T,
// 2048..2559 Wproj^T. Strided 4B gathers; matrices are small (L2-resident).
// ---------------------------------------------------------------------------
__global__ __launch_bounds__(256) void prep_w_pack(
    const float* __restrict__ Wqkv, const float* __restrict__ Wqkv2,
    const float* __restrict__ Wgw, const float* __restrict__ Wproj,
    short* __restrict__ Wp) {
  const int tid = blockIdx.x * 256 + threadIdx.x;   // 163840 total
  const int li = tid & 63, gl = tid >> 6;
  const int kline = gl & 7, group = gl >> 3;
  const int rr = li >> 3, pp = li & 7;
  const int row = group * 8 + rr;                    // 0..2559
  const int k = kline * 64 + ((pp ^ rr) << 3);
  const int n = row & 511, mat = row >> 9;
  const float* W; int ldw, col;
  if (mat == 0)      { W = Wqkv;  ldw = 1536; col = 512 + n; }
  else if (mat == 1) { W = Wqkv2; ldw = 1536; col = n; }
  else if (mat == 2) { W = Wqkv2; ldw = 1536; col = 1024 + n; }
  else if (mat == 3) { W = Wgw;   ldw = 512;  col = n; }
  else               { W = Wproj; ldw = 512;  col = n; }
  unsigned short h[8];
#pragma unroll
  for (int j = 0; j < 8; ++j) h[j] = f2bf(W[(size_t)(k + j) * ldw + col]);
  u32 w0 = (u32)h[0] | ((u32)h[1] << 16);
  u32 w1 = (u32)h[2] | ((u32)h[3] << 16);
  u32 w2 = (u32)h[4] | ((u32)h[5] << 16);
  u32 w3 = (u32)h[6] | ((u32)h[7] << 16);
  ((uint4*)Wp)[tid] = make_uint4(w0, w1, w2, w3);
}

// ---------------------------------------------------------------------------
// GEMM on packed operands: Y[M,128*gridx] = A @ W^T + bias.
// 128x128 tile, BK=64 (8 iters), 4 waves 2x2, 4x4 MFMA tiles x 2 k-steps.
// Staging via global_load_lds 16B (8 issues/wave/iter); frag ds_read_b128
// conflict-free thanks to the XOR-swizzled layout. Blocks with bx>=nsplit
// use the second bias/out set (fused q+v dispatch).
// ---------------------------------------------------------------------------
template <bool OUT_F32>
__global__ __launch_bounds__(256) void gemm_glds(
    const short* __restrict__ Ap, const short* __restrict__ Wp, int wrow0,
    const float* __restrict__ bias0, const float* __restrict__ bias1,
    short* __restrict__ out0, short* __restrict__ out1,
    float* __restrict__ outf, int nsplit) {
  __shared__ short As[128 * 64];
  __shared__ short Bs[128 * 64];

  const int t = threadIdx.x, w = t >> 6, lane = t & 63;
  const int l15 = lane & 15, q = lane >> 4;
  const int wm = w >> 1, wn = w & 1;
  const int bx = blockIdx.x;
  const int row0 = blockIdx.y * 128;
  const int nw0 = wrow0 + bx * 128;
  const int colsel = (bx < nsplit) ? bx : bx - nsplit;
  const float* bias = (bx < nsplit) ? bias0 : bias1;
  short* outb = (bx < nsplit) ? out0 : out1;
  const int col0 = colsel * 128;

  f32x4 acc[4][4];
#pragma unroll
  for (int i = 0; i < 4; ++i)
#pragma unroll
    for (int j = 0; j < 4; ++j) acc[i][j] = {0.f, 0.f, 0.f, 0.f};

  const size_t lb = (size_t)lane * 16;   // lane byte offset within a 1KB line
  const int r7 = l15 & 7, hi8 = l15 >> 3;

  for (int kt = 0; kt < 8; ++kt) {
    __syncthreads();
#pragma unroll
    for (int jj = 0; jj < 4; ++jj) {
      const int rg = w * 4 + jj;
      const char* ga = (const char*)Ap + ((((size_t)(row0 >> 3) + rg) * 8 + kt) << 10);
      glds16(ga + lb, &As[(size_t)rg << 9]);
      const char* gb = (const char*)Wp + ((((size_t)(nw0 >> 3) + rg) * 8 + kt) << 10);
      glds16(gb + lb, &Bs[(size_t)rg << 9]);
    }
    __syncthreads();
#pragma unroll
    for (int s = 0; s < 2; ++s) {
      const int sw = ((s * 4 + q) ^ r7);
      const int pos = (r7 * 8 + sw) * 8;
      bf16x8 af[4], bfr[4];
#pragma unroll
      for (int i = 0; i < 4; ++i)
        af[i] = *(const bf16x8*)&As[((wm * 8 + i * 2 + hi8) << 9) + pos];
#pragma unroll
      for (int j = 0; j < 4; ++j)
        bfr[j] = *(const bf16x8*)&Bs[((wn * 8 + j * 2 + hi8) << 9) + pos];
#pragma unroll
      for (int i = 0; i < 4; ++i)
#pragma unroll
        for (int j = 0; j < 4; ++j)
          acc[i][j] = __builtin_amdgcn_mfma_f32_16x16x32_bf16(af[i], bfr[j],
                                                              acc[i][j], 0, 0, 0);
    }
  }

  // epilogue; C/D layout: row=(lane>>4)*4+reg, col=lane&15
#pragma unroll
  for (int j = 0; j < 4; ++j) {
    const int C = col0 + wn * 64 + j * 16 + l15;
    const float bv = bias[C];
#pragma unroll
    for (int i = 0; i < 4; ++i) {
#pragma unroll
      for (int r = 0; r < 4; ++r) {
        const int R = row0 + wm * 64 + i * 16 + q * 4 + r;
        const float val = acc[i][j][r] + bv;
        if constexpr (OUT_F32)
          outf[(size_t)R * DIMC + C] = val;
        else
          *(short*)((char*)outb + pk_chunk(R, C >> 3) + ((C & 7) << 1)) =
              (short)f2bf(val);
      }
    }
  }
}

// ---------------------------------------------------------------------------
// MFMA attention, one window per wave (unchanged math, packed-layout I/O).
// ---------------------------------------------------------------------------
__global__ __launch_bounds__(256) void attn_mfma(
    const short* __restrict__ kbuf, const short* __restrict__ qbuf,
    const short* __restrict__ vbuf, const short* __restrict__ gbuf,
    const float* __restrict__ a_scalar, short* __restrict__ obuf) {
  __shared__ short pls[4][64 * 40];
  __shared__ short vls[4][32 * 72];

  const int t = threadIdx.x;
  const int w = t >> 6, lane = t & 63;
  const int l15 = lane & 15, q = lane >> 4;
  const int wid = blockIdx.x * 4 + w;
  const int b = wid >> 4, h = wid & 15;
  const int row0 = b * NWIN;
  const float aval = a_scalar[0];
  short* P = pls[w];
  short* VT = vls[w];

#pragma unroll
  for (int it = 0; it < 5; ++it) {
    int off = (it * 64 + lane) * 8;
    if (off < 32 * 72) *(uint4*)&VT[off] = make_uint4(0u, 0u, 0u, 0u);
  }

  bf16x8 kf[4];
#pragma unroll
  for (int mj = 0; mj < 4; ++mj) {
    int m = mj * 16 + l15; if (m > 48) m = 48;
    kf[mj] = *(const bf16x8*)((const char*)kbuf + pk_chunk(row0 + m, h * 4 + q));
  }
  bf16x8 qf[4];
#pragma unroll
  for (int mi = 0; mi < 4; ++mi) {
    int n = mi * 16 + l15; if (n > 48) n = 48;
    const size_t off = pk_chunk(row0 + n, h * 4 + q);
    uint4 qa = *(const uint4*)((const char*)qbuf + off);
    uint4 ga = *(const uint4*)((const char*)gbuf + off);
    u32* qa_ = (u32*)&qa;
    u32* ga_ = (u32*)&ga;
    uint4 res; u32* r_ = (u32*)&res;
#pragma unroll
    for (int jj = 0; jj < 4; ++jj) {
      float lo = bits_f(qa_[jj] << 16) * bits_f(ga_[jj] << 16);
      float hi = bits_f(qa_[jj] & 0xffff0000u) * bits_f(ga_[jj] & 0xffff0000u);
      r_[jj] = (u32)f2bf(lo) | ((u32)f2bf(hi) << 16);
    }
    qf[mi] = *(bf16x8*)&res;
  }
#pragma unroll
  for (int it = 0; it < 4; ++it) {
    int chunk = it * 64 + lane;
    if (chunk < 196) {
      int n = chunk >> 2, dcq = chunk & 3;
      uint4 v = *(const uint4*)((const char*)vbuf + pk_chunk(row0 + n, h * 4 + dcq));
      const short* vs = (const short*)&v;
#pragma unroll
      for (int j = 0; j < 8; ++j) VT[(dcq * 8 + j) * 72 + n] = vs[j];
    }
  }

  f32x4 s[4][4];
#pragma unroll
  for (int mi = 0; mi < 4; ++mi)
#pragma unroll
    for (int nj = 0; nj < 4; ++nj) {
      f32x4 z = {0.f, 0.f, 0.f, 0.f};
      s[mi][nj] = __builtin_amdgcn_mfma_f32_16x16x32_bf16(qf[mi], kf[nj], z, 0, 0, 0);
    }

#pragma unroll
  for (int mi = 0; mi < 4; ++mi)
#pragma unroll
    for (int nj = 0; nj < 4; ++nj) {
      const bool valid = (nj * 16 + l15) < NWIN;
#pragma unroll
      for (int r = 0; r < 4; ++r)
        s[mi][nj][r] = valid ? __expf(ATTN_SCALE * s[mi][nj][r]) : 0.f;
    }

  float lsum[4][4];
#pragma unroll
  for (int mi = 0; mi < 4; ++mi)
#pragma unroll
    for (int r = 0; r < 4; ++r) {
      float part = s[mi][0][r] + s[mi][1][r] + s[mi][2][r] + s[mi][3][r];
      part += __shfl_xor(part, 1, 64);
      part += __shfl_xor(part, 2, 64);
      part += __shfl_xor(part, 4, 64);
      part += __shfl_xor(part, 8, 64);
      lsum[mi][r] = part;
    }

  f32x4 o[4][2];
#pragma unroll
  for (int mi = 0; mi < 4; ++mi)
#pragma unroll
    for (int dj = 0; dj < 2; ++dj) o[mi][dj] = {0.f, 0.f, 0.f, 0.f};

#pragma unroll
  for (int c = 0; c < 2; ++c) {
#pragma unroll
    for (int mi = 0; mi < 4; ++mi)
#pragma unroll
      for (int njh = 0; njh < 2; ++njh) {
        const int nj = c * 2 + njh;
        const int m = nj * 16 + l15;
#pragma unroll
        for (int r = 0; r < 4; ++r) {
          const int n = mi * 16 + q * 4 + r;
          float val = s[mi][nj][r];
          if (m == n) val += aval * lsum[mi][r];
          P[n * 40 + njh * 16 + l15] = (short)f2bf(val);
        }
      }
    bf16x8 bfr[2];
#pragma unroll
    for (int dj = 0; dj < 2; ++dj)
      bfr[dj] = *(const bf16x8*)&VT[(dj * 16 + l15) * 72 + c * 32 + q * 8];
#pragma unroll
    for (int mi = 0; mi < 4; ++mi) {
      bf16x8 af = *(const bf16x8*)&P[(mi * 16 + l15) * 40 + q * 8];
#pragma unroll
      for (int dj = 0; dj < 2; ++dj)
        o[mi][dj] = __builtin_amdgcn_mfma_f32_16x16x32_bf16(af, bfr[dj],
                                                            o[mi][dj], 0, 0, 0);
    }
  }

#pragma unroll
  for (int mi = 0; mi < 4; ++mi)
#pragma unroll
    for (int r = 0; r < 4; ++r) {
      const int n = mi * 16 + q * 4 + r;
      if (n < NWIN) {
        const float rl = 1.0f / lsum[mi][r];
#pragma unroll
        for (int dj = 0; dj < 2; ++dj) {
          const int d = dj * 16 + l15;
          *(short*)((char*)obuf + pk_chunk(row0 + n, h * 4 + (d >> 3)) +
                    ((d & 7) << 1)) = (short)f2bf(o[mi][dj][r] * rl);
        }
      }
    }
}

// ---------------------------------------------------------------------------
extern "C" void kernel_launch(void* const* d_in, const int* in_sizes, int n_in,
                              void* d_out, int out_size, void* d_ws,
                              size_t ws_size, hipStream_t stream) {
  const float* x     = (const float*)d_in[0];
  const float* x2    = (const float*)d_in[1];
  const float* x3    = (const float*)d_in[2];
  const float* Wqkv  = (const float*)d_in[3];
  const float* bqkv  = (const float*)d_in[4];
  const float* Wqkv2 = (const float*)d_in[5];
  const float* bqkv2 = (const float*)d_in[6];
  const float* Wgw   = (const float*)d_in[7];
  const float* bgw   = (const float*)d_in[8];
  const float* Wproj = (const float*)d_in[9];
  const float* bproj = (const float*)d_in[10];
  const float* a     = (const float*)d_in[11];

  char* ws = (char*)d_ws;
  const size_t WTSZ = (size_t)2560 * DIMC * sizeof(short);   // 2.62 MB
  const size_t BSZ  = (size_t)MR * DIMC * sizeof(short);     // 51.4 MB
  short* wt_all = (short*)ws;
  short* cb   = (short*)(ws + WTSZ);            // convbuf, reused serially
  short* kbuf = (short*)(ws + WTSZ + BSZ);
  short* qbuf = (short*)(ws + WTSZ + 2 * BSZ);
  short* vbuf = (short*)(ws + WTSZ + 3 * BSZ);
  short* gbuf = (short*)(ws + WTSZ + 4 * BSZ);  // peak ~259.5 MB
  short* obuf = cb;                             // cb dead after stage-1

  prep_w_pack<<<640, 256, 0, stream>>>(Wqkv, Wqkv2, Wgw, Wproj, wt_all);

  const int convg = MR * DIMC / 8 / 256;        // 12544
  // same-stream kernels serialize, so cb can be safely reused between GEMMs
  conv_pack<<<convg, 256, 0, stream>>>(x, cb);
  gemm_glds<false><<<dim3(4, MR / 128), 256, 0, stream>>>(
      cb, wt_all, 0, bqkv + 512, bqkv + 512, kbuf, kbuf, nullptr, 4);
  conv_pack<<<convg, 256, 0, stream>>>(x3, cb);
  gemm_glds<false><<<dim3(8, MR / 128), 256, 0, stream>>>(
      cb, wt_all, 512, bqkv2, bqkv2 + 1024, qbuf, vbuf, nullptr, 4);
  conv_pack<<<convg, 256, 0, stream>>>(x2, cb);
  gemm_glds<false><<<dim3(4, MR / 128), 256, 0, stream>>>(
      cb, wt_all, 1536, bgw, bgw, gbuf, gbuf, nullptr, 4);

  attn_mfma<<<(NBATCH * NHEADS) / 4, 256, 0, stream>>>(kbuf, qbuf, vbuf, gbuf,
                                                       a, obuf);

  gemm_glds<true><<<dim3(4, MR / 128), 256, 0, stream>>>(
      cb, wt_all, 2048, bproj, bproj, nullptr, nullptr, (float*)d_out, 4);
}

// Round 4
// 626.271 us; speedup vs baseline: 2.3216x; 1.0350x over previous
//
#include <hip/hip_runtime.h>

#define MR 50176        // B_*N = 1024*49 rows
#define DIMC 512
#define NWIN 49
#define NBATCH 1024
#define NHEADS 16
#define ATTN_SCALE 0.17677669529663689f  // 32^-0.5

typedef short bf16x8 __attribute__((ext_vector_type(8)));
typedef float f32x4 __attribute__((ext_vector_type(4)));
typedef unsigned int u32;

__device__ __forceinline__ unsigned short f2bf(float f) {
  union { float f; u32 u; } v; v.f = f;
  u32 u = v.u;
  u += 0x7FFFu + ((u >> 16) & 1u);   // round-to-nearest-even
  return (unsigned short)(u >> 16);
}
__device__ __forceinline__ float bits_f(u32 u) {
  union { u32 u; float f; } v; v.u = u; return v.f;
}

// Packed-swizzled bf16 layout (16B chunks, XOR by row&7) — see R3.
__device__ __forceinline__ size_t pk_chunk(int r, int c) {
  return (((size_t)(r >> 3) * 8 + (c >> 3)) * 64 +
          ((r & 7) * 8 + ((c & 7) ^ (r & 7)))) << 4;
}

typedef const __attribute__((address_space(1))) u32* gp_t;
typedef __attribute__((address_space(3))) u32* lp_t;
__device__ __forceinline__ void glds16(const void* g, void* l) {
  __builtin_amdgcn_global_load_lds((gp_t)g, (lp_t)l, 16, 0, 0);
}

// ---------------------------------------------------------------------------
// fp32 [rows][512] -> packed bf16; up to 3 inputs in one dispatch (grid.y).
// ---------------------------------------------------------------------------
__global__ __launch_bounds__(256) void conv_pack3(
    const float* __restrict__ X0, const float* __restrict__ X1,
    const float* __restrict__ X2, short* __restrict__ P0,
    short* __restrict__ P1, short* __restrict__ P2) {
  const float* X = (blockIdx.y == 0) ? X0 : (blockIdx.y == 1) ? X1 : X2;
  short* Xp = (blockIdx.y == 0) ? P0 : (blockIdx.y == 1) ? P1 : P2;
  const int tid = blockIdx.x * 256 + threadIdx.x;
  const int li = tid & 63, gl = tid >> 6;
  const int kline = gl & 7, group = gl >> 3;
  const int rr = li >> 3, pp = li & 7;
  const int row = group * 8 + rr;
  const int k = kline * 64 + ((pp ^ rr) << 3);
  const float* src = X + (size_t)row * DIMC + k;
  const float4 a = *(const float4*)src;
  const float4 b = *(const float4*)(src + 4);
  u32 w0 = (u32)f2bf(a.x) | ((u32)f2bf(a.y) << 16);
  u32 w1 = (u32)f2bf(a.z) | ((u32)f2bf(a.w) << 16);
  u32 w2 = (u32)f2bf(b.x) | ((u32)f2bf(b.y) << 16);
  u32 w3 = (u32)f2bf(b.z) | ((u32)f2bf(b.w) << 16);
  ((uint4*)Xp)[tid] = make_uint4(w0, w1, w2, w3);
}

// ---------------------------------------------------------------------------
// 5 weight slices -> one packed bf16 [2560][512] (k,q,v,g,proj transposed).
// ---------------------------------------------------------------------------
__global__ __launch_bounds__(256) void prep_w_pack(
    const float* __restrict__ Wqkv, const float* __restrict__ Wqkv2,
    const float* __restrict__ Wgw, const float* __restrict__ Wproj,
    short* __restrict__ Wp) {
  const int tid = blockIdx.x * 256 + threadIdx.x;   // 163840 total
  const int li = tid & 63, gl = tid >> 6;
  const int kline = gl & 7, group = gl >> 3;
  const int rr = li >> 3, pp = li & 7;
  const int row = group * 8 + rr;                    // 0..2559
  const int k = kline * 64 + ((pp ^ rr) << 3);
  const int n = row & 511, mat = row >> 9;
  const float* W; int ldw, col;
  if (mat == 0)      { W = Wqkv;  ldw = 1536; col = 512 + n; }
  else if (mat == 1) { W = Wqkv2; ldw = 1536; col = n; }
  else if (mat == 2) { W = Wqkv2; ldw = 1536; col = 1024 + n; }
  else if (mat == 3) { W = Wgw;   ldw = 512;  col = n; }
  else               { W = Wproj; ldw = 512;  col = n; }
  unsigned short h[8];
#pragma unroll
  for (int j = 0; j < 8; ++j) h[j] = f2bf(W[(size_t)(k + j) * ldw + col]);
  u32 w0 = (u32)h[0] | ((u32)h[1] << 16);
  u32 w1 = (u32)h[2] | ((u32)h[3] << 16);
  u32 w2 = (u32)h[4] | ((u32)h[5] << 16);
  u32 w3 = (u32)h[6] | ((u32)h[7] << 16);
  ((uint4*)Wp)[tid] = make_uint4(w0, w1, w2, w3);
}

// ---------------------------------------------------------------------------
// Multi-output GEMM on packed operands, XCD-swizzled 1D grid of NX*392.
// id -> xcd=id&7, slot=id>>3, bx=slot&(NX-1), y=xcd+8*(slot>>LNX):
// consecutive slots on one XCD sweep bx for the SAME A-row-tile (L2 reuse);
// XCDs own disjoint y. Per-bx unit select (k/q/v/g) via by-value cfg.
// ---------------------------------------------------------------------------
struct GemmCfg {
  const short* A[4];
  const float* bias[4];
  short* out[4];
  int wrow0[4];
};

template <int LNX, bool OUT_F32>
__global__ __launch_bounds__(256) void gemm_glds(
    GemmCfg cfg, const short* __restrict__ Wp, float* __restrict__ outf) {
  __shared__ short As[128 * 64];
  __shared__ short Bs[128 * 64];

  const int t = threadIdx.x, w = t >> 6, lane = t & 63;
  const int l15 = lane & 15, q = lane >> 4;
  const int wm = w >> 1, wn = w & 1;
  const int id = blockIdx.x;
  const int xcd = id & 7, slot = id >> 3;
  const int bx = slot & ((1 << LNX) - 1);
  const int y = xcd + ((slot >> LNX) << 3);
  const int row0 = y * 128;
  const int unit = bx >> 2, sub = bx & 3;
  const short* Ap = cfg.A[unit];
  const float* bias = cfg.bias[unit];
  short* outb = cfg.out[unit];
  const int nw0 = cfg.wrow0[unit] + sub * 128;
  const int col0 = sub * 128;

  f32x4 acc[4][4];
#pragma unroll
  for (int i = 0; i < 4; ++i)
#pragma unroll
    for (int j = 0; j < 4; ++j) acc[i][j] = {0.f, 0.f, 0.f, 0.f};

  const size_t lb = (size_t)lane * 16;
  const int r7 = l15 & 7, hi8 = l15 >> 3;

  for (int kt = 0; kt < 8; ++kt) {
    __syncthreads();
#pragma unroll
    for (int jj = 0; jj < 4; ++jj) {
      const int rg = w * 4 + jj;
      const char* ga = (const char*)Ap + ((((size_t)(row0 >> 3) + rg) * 8 + kt) << 10);
      glds16(ga + lb, &As[(size_t)rg << 9]);
      const char* gb = (const char*)Wp + ((((size_t)(nw0 >> 3) + rg) * 8 + kt) << 10);
      glds16(gb + lb, &Bs[(size_t)rg << 9]);
    }
    __syncthreads();
#pragma unroll
    for (int s = 0; s < 2; ++s) {
      const int sw = ((s * 4 + q) ^ r7);
      const int pos = (r7 * 8 + sw) * 8;
      bf16x8 af[4], bfr[4];
#pragma unroll
      for (int i = 0; i < 4; ++i)
        af[i] = *(const bf16x8*)&As[((wm * 8 + i * 2 + hi8) << 9) + pos];
#pragma unroll
      for (int j = 0; j < 4; ++j)
        bfr[j] = *(const bf16x8*)&Bs[((wn * 8 + j * 2 + hi8) << 9) + pos];
#pragma unroll
      for (int i = 0; i < 4; ++i)
#pragma unroll
        for (int j = 0; j < 4; ++j)
          acc[i][j] = __builtin_amdgcn_mfma_f32_16x16x32_bf16(af[i], bfr[j],
                                                              acc[i][j], 0, 0, 0);
    }
  }

#pragma unroll
  for (int j = 0; j < 4; ++j) {
    const int C = col0 + wn * 64 + j * 16 + l15;
    const float bv = bias[C];
#pragma unroll
    for (int i = 0; i < 4; ++i) {
#pragma unroll
      for (int r = 0; r < 4; ++r) {
        const int R = row0 + wm * 64 + i * 16 + q * 4 + r;
        const float val = acc[i][j][r] + bv;
        if constexpr (OUT_F32)
          outf[(size_t)R * DIMC + C] = val;
        else
          *(short*)((char*)outb + pk_chunk(R, C >> 3) + ((C & 7) << 1)) =
              (short)f2bf(val);
      }
    }
  }
}

// ---------------------------------------------------------------------------
// MFMA attention, one window per wave (unchanged from R3; packed I/O).
// ---------------------------------------------------------------------------
__global__ __launch_bounds__(256) void attn_mfma(
    const short* __restrict__ kbuf, const short* __restrict__ qbuf,
    const short* __restrict__ vbuf, const short* __restrict__ gbuf,
    const float* __restrict__ a_scalar, short* __restrict__ obuf) {
  __shared__ short pls[4][64 * 40];
  __shared__ short vls[4][32 * 72];

  const int t = threadIdx.x;
  const int w = t >> 6, lane = t & 63;
  const int l15 = lane & 15, q = lane >> 4;
  const int wid = blockIdx.x * 4 + w;
  const int b = wid >> 4, h = wid & 15;
  const int row0 = b * NWIN;
  const float aval = a_scalar[0];
  short* P = pls[w];
  short* VT = vls[w];

#pragma unroll
  for (int it = 0; it < 5; ++it) {
    int off = (it * 64 + lane) * 8;
    if (off < 32 * 72) *(uint4*)&VT[off] = make_uint4(0u, 0u, 0u, 0u);
  }

  bf16x8 kf[4];
#pragma unroll
  for (int mj = 0; mj < 4; ++mj) {
    int m = mj * 16 + l15; if (m > 48) m = 48;
    kf[mj] = *(const bf16x8*)((const char*)kbuf + pk_chunk(row0 + m, h * 4 + q));
  }
  bf16x8 qf[4];
#pragma unroll
  for (int mi = 0; mi < 4; ++mi) {
    int n = mi * 16 + l15; if (n > 48) n = 48;
    const size_t off = pk_chunk(row0 + n, h * 4 + q);
    uint4 qa = *(const uint4*)((const char*)qbuf + off);
    uint4 ga = *(const uint4*)((const char*)gbuf + off);
    u32* qa_ = (u32*)&qa;
    u32* ga_ = (u32*)&ga;
    uint4 res; u32* r_ = (u32*)&res;
#pragma unroll
    for (int jj = 0; jj < 4; ++jj) {
      float lo = bits_f(qa_[jj] << 16) * bits_f(ga_[jj] << 16);
      float hi = bits_f(qa_[jj] & 0xffff0000u) * bits_f(ga_[jj] & 0xffff0000u);
      r_[jj] = (u32)f2bf(lo) | ((u32)f2bf(hi) << 16);
    }
    qf[mi] = *(bf16x8*)&res;
  }
#pragma unroll
  for (int it = 0; it < 4; ++it) {
    int chunk = it * 64 + lane;
    if (chunk < 196) {
      int n = chunk >> 2, dcq = chunk & 3;
      uint4 v = *(const uint4*)((const char*)vbuf + pk_chunk(row0 + n, h * 4 + dcq));
      const short* vs = (const short*)&v;
#pragma unroll
      for (int j = 0; j < 8; ++j) VT[(dcq * 8 + j) * 72 + n] = vs[j];
    }
  }

  f32x4 s[4][4];
#pragma unroll
  for (int mi = 0; mi < 4; ++mi)
#pragma unroll
    for (int nj = 0; nj < 4; ++nj) {
      f32x4 z = {0.f, 0.f, 0.f, 0.f};
      s[mi][nj] = __builtin_amdgcn_mfma_f32_16x16x32_bf16(qf[mi], kf[nj], z, 0, 0, 0);
    }

#pragma unroll
  for (int mi = 0; mi < 4; ++mi)
#pragma unroll
    for (int nj = 0; nj < 4; ++nj) {
      const bool valid = (nj * 16 + l15) < NWIN;
#pragma unroll
      for (int r = 0; r < 4; ++r)
        s[mi][nj][r] = valid ? __expf(ATTN_SCALE * s[mi][nj][r]) : 0.f;
    }

  float lsum[4][4];
#pragma unroll
  for (int mi = 0; mi < 4; ++mi)
#pragma unroll
    for (int r = 0; r < 4; ++r) {
      float part = s[mi][0][r] + s[mi][1][r] + s[mi][2][r] + s[mi][3][r];
      part += __shfl_xor(part, 1, 64);
      part += __shfl_xor(part, 2, 64);
      part += __shfl_xor(part, 4, 64);
      part += __shfl_xor(part, 8, 64);
      lsum[mi][r] = part;
    }

  f32x4 o[4][2];
#pragma unroll
  for (int mi = 0; mi < 4; ++mi)
#pragma unroll
    for (int dj = 0; dj < 2; ++dj) o[mi][dj] = {0.f, 0.f, 0.f, 0.f};

#pragma unroll
  for (int c = 0; c < 2; ++c) {
#pragma unroll
    for (int mi = 0; mi < 4; ++mi)
#pragma unroll
      for (int njh = 0; njh < 2; ++njh) {
        const int nj = c * 2 + njh;
        const int m = nj * 16 + l15;
#pragma unroll
        for (int r = 0; r < 4; ++r) {
          const int n = mi * 16 + q * 4 + r;
          float val = s[mi][nj][r];
          if (m == n) val += aval * lsum[mi][r];
          P[n * 40 + njh * 16 + l15] = (short)f2bf(val);
        }
      }
    bf16x8 bfr[2];
#pragma unroll
    for (int dj = 0; dj < 2; ++dj)
      bfr[dj] = *(const bf16x8*)&VT[(dj * 16 + l15) * 72 + c * 32 + q * 8];
#pragma unroll
    for (int mi = 0; mi < 4; ++mi) {
      bf16x8 af = *(const bf16x8*)&P[(mi * 16 + l15) * 40 + q * 8];
#pragma unroll
      for (int dj = 0; dj < 2; ++dj)
        o[mi][dj] = __builtin_amdgcn_mfma_f32_16x16x32_bf16(af, bfr[dj],
                                                            o[mi][dj], 0, 0, 0);
    }
  }

#pragma unroll
  for (int mi = 0; mi < 4; ++mi)
#pragma unroll
    for (int r = 0; r < 4; ++r) {
      const int n = mi * 16 + q * 4 + r;
      if (n < NWIN) {
        const float rl = 1.0f / lsum[mi][r];
#pragma unroll
        for (int dj = 0; dj < 2; ++dj) {
          const int d = dj * 16 + l15;
          *(short*)((char*)obuf + pk_chunk(row0 + n, h * 4 + (d >> 3)) +
                    ((d & 7) << 1)) = (short)f2bf(o[mi][dj][r] * rl);
        }
      }
    }
}

// ---------------------------------------------------------------------------
extern "C" void kernel_launch(void* const* d_in, const int* in_sizes, int n_in,
                              void* d_out, int out_size, void* d_ws,
                              size_t ws_size, hipStream_t stream) {
  const float* x     = (const float*)d_in[0];
  const float* x2    = (const float*)d_in[1];
  const float* x3    = (const float*)d_in[2];
  const float* Wqkv  = (const float*)d_in[3];
  const float* bqkv  = (const float*)d_in[4];
  const float* Wqkv2 = (const float*)d_in[5];
  const float* bqkv2 = (const float*)d_in[6];
  const float* Wgw   = (const float*)d_in[7];
  const float* bgw   = (const float*)d_in[8];
  const float* Wproj = (const float*)d_in[9];
  const float* bproj = (const float*)d_in[10];
  const float* a     = (const float*)d_in[11];

  char* ws = (char*)d_ws;
  const size_t WTSZ = (size_t)2560 * DIMC * sizeof(short);   // 2.62 MB
  const size_t BSZ  = (size_t)MR * DIMC * sizeof(short);     // 51.4 MB
  short* wt_all = (short*)ws;

  prep_w_pack<<<640, 256, 0, stream>>>(Wqkv, Wqkv2, Wgw, Wproj, wt_all);

  const int convg = MR * DIMC / 8 / 256;        // 12544

  if (ws_size >= WTSZ + 7 * BSZ) {
    // ---------------- fused path (362 MB workspace) ----------------
    short* xp   = (short*)(ws + WTSZ);
    short* x2p  = (short*)(ws + WTSZ + BSZ);
    short* x3p  = (short*)(ws + WTSZ + 2 * BSZ);
    short* kbuf = (short*)(ws + WTSZ + 3 * BSZ);
    short* qbuf = (short*)(ws + WTSZ + 4 * BSZ);
    short* vbuf = (short*)(ws + WTSZ + 5 * BSZ);
    short* gbuf = (short*)(ws + WTSZ + 6 * BSZ);
    short* obuf = xp;  // xp dead after stage-1

    conv_pack3<<<dim3(convg, 3), 256, 0, stream>>>(x, x2, x3, xp, x2p, x3p);

    GemmCfg s1;
    s1.A[0] = xp;  s1.A[1] = x3p; s1.A[2] = x3p; s1.A[3] = x2p;
    s1.bias[0] = bqkv + 512; s1.bias[1] = bqkv2;
    s1.bias[2] = bqkv2 + 1024; s1.bias[3] = bgw;
    s1.out[0] = kbuf; s1.out[1] = qbuf; s1.out[2] = vbuf; s1.out[3] = gbuf;
    s1.wrow0[0] = 0; s1.wrow0[1] = 512; s1.wrow0[2] = 1024; s1.wrow0[3] = 1536;
    gemm_glds<4, false><<<16 * 392, 256, 0, stream>>>(s1, wt_all, nullptr);

    attn_mfma<<<(NBATCH * NHEADS) / 4, 256, 0, stream>>>(kbuf, qbuf, vbuf,
                                                         gbuf, a, obuf);

    GemmCfg pj = {};
    pj.A[0] = obuf; pj.bias[0] = bproj; pj.out[0] = nullptr; pj.wrow0[0] = 2048;
    gemm_glds<2, true><<<4 * 392, 256, 0, stream>>>(pj, wt_all, (float*)d_out);
  } else {
    // ---------------- serial fallback (259.5 MB) ----------------
    short* cb   = (short*)(ws + WTSZ);
    short* kbuf = (short*)(ws + WTSZ + BSZ);
    short* qbuf = (short*)(ws + WTSZ + 2 * BSZ);
    short* vbuf = (short*)(ws + WTSZ + 3 * BSZ);
    short* gbuf = (short*)(ws + WTSZ + 4 * BSZ);
    short* obuf = cb;

    conv_pack3<<<dim3(convg, 1), 256, 0, stream>>>(x, x, x, cb, cb, cb);
    GemmCfg ck = {};
    ck.A[0] = cb; ck.bias[0] = bqkv + 512; ck.out[0] = kbuf; ck.wrow0[0] = 0;
    gemm_glds<2, false><<<4 * 392, 256, 0, stream>>>(ck, wt_all, nullptr);

    conv_pack3<<<dim3(convg, 1), 256, 0, stream>>>(x3, x3, x3, cb, cb, cb);
    GemmCfg cqv = {};
    cqv.A[0] = cb; cqv.A[1] = cb;
    cqv.bias[0] = bqkv2; cqv.bias[1] = bqkv2 + 1024;
    cqv.out[0] = qbuf; cqv.out[1] = vbuf;
    cqv.wrow0[0] = 512; cqv.wrow0[1] = 1024;
    gemm_glds<3, false><<<8 * 392, 256, 0, stream>>>(cqv, wt_all, nullptr);

    conv_pack3<<<dim3(convg, 1), 256, 0, stream>>>(x2, x2, x2, cb, cb, cb);
    GemmCfg cg = {};
    cg.A[0] = cb; cg.bias[0] = bgw; cg.out[0] = gbuf; cg.wrow0[0] = 1536;
    gemm_glds<2, false><<<4 * 392, 256, 0, stream>>>(cg, wt_all, nullptr);

    attn_mfma<<<(NBATCH * NHEADS) / 4, 256, 0, stream>>>(kbuf, qbuf, vbuf,
                                                         gbuf, a, obuf);

    GemmCfg pj = {};
    pj.A[0] = obuf; pj.bias[0] = bproj; pj.wrow0[0] = 2048;
    gemm_glds<2, true><<<4 * 392, 256, 0, stream>>>(pj, wt_all, (float*)d_out);
  }
}